// Round 9
// baseline (557.592 us; speedup 1.0000x reference)
//
#include <hip/hip_runtime.h>
#include <math.h>

#define B_   64
#define T_   500
#define IN_  1024
#define G_   8
#define HG_  128
#define J3_  384   // 3*HG

typedef _Float16 half8 __attribute__((ext_vector_type(8)));
typedef _Float16 half4 __attribute__((ext_vector_type(4)));
typedef float    f32x4 __attribute__((ext_vector_type(4)));

static __device__ __forceinline__ half8 cvt_half8(const float* p) {
    const float4 a = *(const float4*)p;
    const float4 b = *(const float4*)(p + 4);
    half8 h;
    h[0] = (_Float16)a.x; h[1] = (_Float16)a.y; h[2] = (_Float16)a.z; h[3] = (_Float16)a.w;
    h[4] = (_Float16)b.x; h[5] = (_Float16)b.y; h[6] = (_Float16)b.z; h[7] = (_Float16)b.w;
    return h;
}

// opaque reg-to-reg barrier: prevents rematerialization of loop-invariant
// loaded values (rounds 2/4/8 disease: allocator re-executes invariant global
// loads inside the recurrence loop instead of keeping them resident).
static __device__ __forceinline__ void pin_frag(half8& h) {
    f32x4 t = __builtin_bit_cast(f32x4, h);
    float a = t[0], b = t[1], c = t[2], d = t[3];
    asm volatile("" : "+v"(a), "+v"(b), "+v"(c), "+v"(d));
    t[0] = a; t[1] = b; t[2] = c; t[3] = d;
    h = __builtin_bit_cast(half8, t);
}
static __device__ __forceinline__ void pin_f32x4(f32x4& v) {
    float a = v[0], b = v[1], c = v[2], d = v[3];
    asm volatile("" : "+v"(a), "+v"(b), "+v"(c), "+v"(d));
    v[0] = a; v[1] = b; v[2] = c; v[3] = d;
}

// LDS-only barrier: orders ds ops across the workgroup WITHOUT draining vmcnt
// (x prefetch loads and out stores stay in flight across steps).
static __device__ __forceinline__ void barrier_lds_only() {
    asm volatile("s_waitcnt lgkmcnt(0)\n\ts_barrier" ::: "memory");
}

// ---------------------------------------------------------------------------
// Kernel 0: cast x (fp32) -> x16 (f16), one-shot, memory-bound (~15 us).
// ---------------------------------------------------------------------------
__global__ __launch_bounds__(256)
void cvt_x(const float* __restrict__ x, _Float16* __restrict__ x16)
{
    const size_t n4 = (size_t)B_ * T_ * IN_ / 4;
    const size_t stride = (size_t)gridDim.x * 256;
    for (size_t i = (size_t)blockIdx.x * 256 + threadIdx.x; i < n4; i += stride) {
        const float4 v = ((const float4*)x)[i];
        half4 h;
        h[0] = (_Float16)v.x; h[1] = (_Float16)v.y;
        h[2] = (_Float16)v.z; h[3] = (_Float16)v.w;
        ((half4*)x16)[i] = h;
    }
}

// ---------------------------------------------------------------------------
// Kernel 1 (structure G2 + full residency): fused GRU.
// 32 blocks x 512 thr; 16 sequences per block (MFMA col = seq = lr).
// amdgpu_waves_per_eu(1,2): tell the allocator only <=2 waves/EU are resident
// so the VGPR cap is 256 (launch_bounds 2nd arg alone left us at a 128-ish
// cap -> VGPR_Count 104 < 166 live -> biases rematerialized as per-step
// global loads on the serial chain; the round-8 un-modeled ~1500cy stall).
// All loop-invariant LOADED state is asm-pinned: W frags (96) + biases (16).
// ---------------------------------------------------------------------------
__global__ __launch_bounds__(512, 1) __attribute__((amdgpu_waves_per_eu(1, 2)))
void gru_fused(const float* __restrict__ Wih, const float* __restrict__ Whh,
               const float* __restrict__ bih, const float* __restrict__ bhh,
               const _Float16* __restrict__ x16, float* __restrict__ out)
{
    const int tid  = threadIdx.x;
    const int lane = tid & 63;
    const int w    = tid >> 6;        // wave 0..7 == j-tile
    const int lr   = lane & 15;       // seq within block / MFMA col
    const int hi   = lane >> 4;       // 0..3
    const int blk  = blockIdx.x;      // 0..31
    const int g    = blk & 7;
    const int bq   = blk >> 3;        // 0..3
    const int b    = bq * 16 + lr;    // this lane's sequence
    const int jl   = w * 16 + hi * 4; // this lane's j base (4 consecutive)

    __shared__ _Float16 hmem[2][16 * 128];   // [buf][swizzled seq-major], 8 KB

    // ---- persistent pinned fragments: rows p*128 + 16w + lr, k = kt*32+hi*8 ----
    half8 aI[3][4], aH[3][4];
#pragma unroll
    for (int p = 0; p < 3; ++p)
#pragma unroll
        for (int kt = 0; kt < 4; ++kt) {
            const size_t roff = (size_t)(g * J3_ + p * 128 + w * 16 + lr) * HG_
                              + kt * 32 + hi * 8;
            aI[p][kt] = cvt_half8(Wih + roff);  pin_frag(aI[p][kt]);
            aH[p][kt] = cvt_half8(Whh + roff);  pin_frag(aH[p][kt]);
        }

    // ---- biases for this lane's 4 j's; r,z: bih+bhh fused into x-chain seed;
    //      n: bih seeds x-chain, bhh seeds h-chain. ALL PINNED (no remat). ----
    const float* bi = bih + g * J3_;
    const float* bh = bhh + g * J3_;
    f32x4 brz0, brz1, bin_, bhn_;
    {
        const f32x4 i0 = *(const f32x4*)(bi + jl);
        const f32x4 h0 = *(const f32x4*)(bh + jl);
        const f32x4 i1 = *(const f32x4*)(bi + 128 + jl);
        const f32x4 h1 = *(const f32x4*)(bh + 128 + jl);
        brz0 = i0 + h0; brz1 = i1 + h1;
        bin_ = *(const f32x4*)(bi + 256 + jl);
        bhn_ = *(const f32x4*)(bh + 256 + jl);
        pin_f32x4(brz0); pin_f32x4(brz1); pin_f32x4(bin_); pin_f32x4(bhn_);
    }

    // ---- h = 0 init (each lane writes its own swizzled slot in buf 0) ----
    f32x4 hreg = (f32x4){0.f, 0.f, 0.f, 0.f};
    {
        const int gi = (2 * w + (hi >> 1)) ^ (lr & 7);
        half4 z4 = (half4){(_Float16)0.f, (_Float16)0.f, (_Float16)0.f, (_Float16)0.f};
        *(half4*)&hmem[0][lr * 128 + gi * 8 + (hi & 1) * 4] = z4;
    }

    const _Float16* xrow = x16 + (size_t)b * T_ * IN_ + g * HG_;   // + tau*IN_
    float*          orow = out + (size_t)b * T_ * IN_ + g * HG_;   // + tau*IN_

    // ---- prologue: bxB <- x(0), bxA <- x(1); xaA = xproj(x(0)) ----
    half8 bxA[4], bxB[4];
#pragma unroll
    for (int kt = 0; kt < 4; ++kt) bxB[kt] = *(const half8*)(xrow + kt * 32 + hi * 8);
#pragma unroll
    for (int kt = 0; kt < 4; ++kt) bxA[kt] = *(const half8*)(xrow + IN_ + kt * 32 + hi * 8);

    f32x4 xaA0 = brz0, xaA1 = brz1, xaA2 = bin_;
#pragma unroll
    for (int kt = 0; kt < 4; ++kt) {
        xaA0 = __builtin_amdgcn_mfma_f32_16x16x32_f16(aI[0][kt], bxB[kt], xaA0, 0, 0, 0);
        xaA1 = __builtin_amdgcn_mfma_f32_16x16x32_f16(aI[1][kt], bxB[kt], xaA1, 0, 0, 0);
        xaA2 = __builtin_amdgcn_mfma_f32_16x16x32_f16(aI[2][kt], bxB[kt], xaA2, 0, 0, 0);
    }
    f32x4 xaB0, xaB1, xaB2;

    __syncthreads();   // full barrier once, outside the loop

    // NOTE on x16 over-read: steps t=498,499 prefetch/project x(500),x(501)
    // (results unused). That reads <=4KB past the 65.5MB x16 region, still
    // inside d_ws. Safe garbage.

#define GRU_STEP(TAU, BXc, BXn, xc0, xc1, xc2, xn0, xn1, xn2)                      \
    do {                                                                           \
        const int pb = (TAU) & 1;                                                  \
        /* 1. h B-frags: issue ds_reads first (latency hidden by 2&3) */           \
        const half8 bf0 = *(const half8*)&hmem[pb][lr * 128 + (( 0 + hi) ^ (lr & 7)) * 8]; \
        const half8 bf1 = *(const half8*)&hmem[pb][lr * 128 + (( 4 + hi) ^ (lr & 7)) * 8]; \
        const half8 bf2 = *(const half8*)&hmem[pb][lr * 128 + (( 8 + hi) ^ (lr & 7)) * 8]; \
        const half8 bf3 = *(const half8*)&hmem[pb][lr * 128 + ((12 + hi) ^ (lr & 7)) * 8]; \
        /* 2. x-projection for TAU+1 (bias-seeded; h-independent filler) */        \
        xn0 = brz0; xn1 = brz1; xn2 = bin_;                                        \
        _Pragma("unroll")                                                          \
        for (int kt = 0; kt < 4; ++kt) {                                           \
            xn0 = __builtin_amdgcn_mfma_f32_16x16x32_f16(aI[0][kt], BXc[kt], xn0, 0, 0, 0); \
            xn1 = __builtin_amdgcn_mfma_f32_16x16x32_f16(aI[1][kt], BXc[kt], xn1, 0, 0, 0); \
            xn2 = __builtin_amdgcn_mfma_f32_16x16x32_f16(aI[2][kt], BXc[kt], xn2, 0, 0, 0); \
        }                                                                          \
        /* 3. reload BXn <- x(TAU+2); stays in flight across barriers */           \
        {                                                                          \
            const _Float16* px = xrow + (size_t)((TAU) + 2) * IN_;                 \
            _Pragma("unroll")                                                      \
            for (int kt = 0; kt < 4; ++kt)                                         \
                BXn[kt] = *(const half8*)(px + kt * 32 + hi * 8);                  \
        }                                                                          \
        /* 4. h-MFMA, split 2+2 chains per gate (shorter dep path) */              \
        f32x4 h0a = (f32x4){0.f,0.f,0.f,0.f}, h0b = h0a;                           \
        f32x4 h1a = h0a, h1b = h0a, h2b = h0a;                                     \
        f32x4 h2a = bhn_;                                                          \
        h0a = __builtin_amdgcn_mfma_f32_16x16x32_f16(aH[0][0], bf0, h0a, 0, 0, 0); \
        h1a = __builtin_amdgcn_mfma_f32_16x16x32_f16(aH[1][0], bf0, h1a, 0, 0, 0); \
        h2a = __builtin_amdgcn_mfma_f32_16x16x32_f16(aH[2][0], bf0, h2a, 0, 0, 0); \
        h0b = __builtin_amdgcn_mfma_f32_16x16x32_f16(aH[0][2], bf2, h0b, 0, 0, 0); \
        h1b = __builtin_amdgcn_mfma_f32_16x16x32_f16(aH[1][2], bf2, h1b, 0, 0, 0); \
        h2b = __builtin_amdgcn_mfma_f32_16x16x32_f16(aH[2][2], bf2, h2b, 0, 0, 0); \
        h0a = __builtin_amdgcn_mfma_f32_16x16x32_f16(aH[0][1], bf1, h0a, 0, 0, 0); \
        h1a = __builtin_amdgcn_mfma_f32_16x16x32_f16(aH[1][1], bf1, h1a, 0, 0, 0); \
        h2a = __builtin_amdgcn_mfma_f32_16x16x32_f16(aH[2][1], bf1, h2a, 0, 0, 0); \
        h0b = __builtin_amdgcn_mfma_f32_16x16x32_f16(aH[0][3], bf3, h0b, 0, 0, 0); \
        h1b = __builtin_amdgcn_mfma_f32_16x16x32_f16(aH[1][3], bf3, h1b, 0, 0, 0); \
        h2b = __builtin_amdgcn_mfma_f32_16x16x32_f16(aH[2][3], bf3, h2b, 0, 0, 0); \
        const f32x4 ha0 = h0a + h0b;                                               \
        const f32x4 ha1 = h1a + h1b;                                               \
        const f32x4 ha2 = h2a + h2b;                                               \
        /* 5. lane-local gates (seq = lr, 4 j's); biases pre-seeded */             \
        f32x4 hnew;                                                                \
        _Pragma("unroll")                                                          \
        for (int r = 0; r < 4; ++r) {                                              \
            const float ar  = xc0[r] + ha0[r];                                     \
            const float az  = xc1[r] + ha1[r];                                     \
            const float rg = __builtin_amdgcn_rcpf(1.f + __builtin_amdgcn_exp2f(-1.4426950f * ar)); \
            const float zg = __builtin_amdgcn_rcpf(1.f + __builtin_amdgcn_exp2f(-1.4426950f * az)); \
            const float pre = xc2[r] + rg * ha2[r];                                \
            const float th  = 2.f * __builtin_amdgcn_rcpf(1.f + __builtin_amdgcn_exp2f(-2.8853900f * pre)) - 1.f; \
            hnew[r] = th + zg * (hreg[r] - th);                                    \
        }                                                                          \
        hreg = hnew;                                                               \
        /* 6. write h for next step (swizzled), lds-only barrier */                \
        {                                                                          \
            half4 hh;                                                              \
            _Pragma("unroll")                                                      \
            for (int r = 0; r < 4; ++r) hh[r] = (_Float16)hnew[r];                 \
            const int gi = (2 * w + (hi >> 1)) ^ (lr & 7);                         \
            *(half4*)&hmem[pb ^ 1][lr * 128 + gi * 8 + (hi & 1) * 4] = hh;         \
        }                                                                          \
        barrier_lds_only();                                                        \
        /* 7. out store AFTER barrier: lands in next step's ds-wait window */      \
        *(f32x4*)(orow + (size_t)(TAU) * IN_ + jl) = hnew;                         \
    } while (0)

    for (int t = 0; t < T_; t += 2) {
        GRU_STEP(t,     bxA, bxB, xaA0, xaA1, xaA2, xaB0, xaB1, xaB2);
        GRU_STEP(t + 1, bxB, bxA, xaB0, xaB1, xaB2, xaA0, xaA1, xaA2);
    }
#undef GRU_STEP
}

// ---------------------------------------------------------------------------
extern "C" void kernel_launch(void* const* d_in, const int* in_sizes, int n_in,
                              void* d_out, int out_size, void* d_ws, size_t ws_size,
                              hipStream_t stream) {
    (void)in_sizes; (void)n_in; (void)out_size; (void)ws_size;
    const float* x   = (const float*)d_in[0];
    const float* Wih = (const float*)d_in[1];
    const float* Whh = (const float*)d_in[2];
    const float* bih = (const float*)d_in[3];
    const float* bhh = (const float*)d_in[4];
    float* out = (float*)d_out;

    _Float16* x16 = (_Float16*)d_ws;    // 65.5 MB (+<=4KB over-read slack)

    cvt_x<<<4096, 256, 0, stream>>>(x, x16);
    gru_fused<<<32, 512, 0, stream>>>(Wih, Whh, bih, bhh, x16, out);
}